// Round 1
// baseline (282.258 us; speedup 1.0000x reference)
//
#include <hip/hip_runtime.h>

#define K_CODES 4096
#define DIM 256
#define SEQ 2048
#define NTOK 65536

typedef __bf16 bf16x8 __attribute__((ext_vector_type(8)));
typedef float floatx4 __attribute__((ext_vector_type(4)));
typedef unsigned short u16x8 __attribute__((ext_vector_type(8)));

__device__ __forceinline__ unsigned short f2bf(float f) {
    union { float f; unsigned int u; } v; v.f = f;
    unsigned int u = v.u;
    unsigned int r = u + 0x7fffu + ((u >> 16) & 1u);   // RNE
    return (unsigned short)(r >> 16);
}

// async global->LDS, 16B per lane. LDS dest = wave-uniform base + lane*16.
__device__ __forceinline__ void async_cp16(const void* g, const void* lds_base) {
    typedef __attribute__((address_space(1))) const unsigned int guint;
    typedef __attribute__((address_space(3))) unsigned int luint;
    __builtin_amdgcn_global_load_lds(
        (guint*)(unsigned long long)g,
        (luint*)(unsigned int)(unsigned long long)lds_base,
        16, 0, 0);
}

// ---------------- kernel 1: swizzled bf16 codebook + biased norms -----------
// cb_swz[((gc*16 + ns*8 + ks)*64 + quad*16 + col)*8 + j]
//   = bf16(codebook[gc*32 + ns*16 + col][quad*8 + ks*32 + j])
// norms[row] = ||e||^2 + 0.25 (bias keeps dist positive; exp ~ -2 -> key
// truncation quantum 2^-13..2^-14, well under the 2.2e-3 code-distance std)
__global__ __launch_bounds__(256) void k_prep(const float* __restrict__ cb,
        unsigned short* __restrict__ cb_swz, float* __restrict__ norms,
        float* __restrict__ loss_slot) {
    const int c = blockIdx.x;
    const int t = threadIdx.x;
    const int row_loc = t >> 3;       // 0..31 code within chunk
    const int ks = t & 7;             // k-slice
    const int row = c * 32 + row_loc;
    const float* src = cb + (size_t)row * DIM + ks * 32;
    float vals[32];
    float s = 0.0f;
    #pragma unroll
    for (int i = 0; i < 8; ++i) {
        floatx4 v = *(const floatx4*)(src + i * 4);
        #pragma unroll
        for (int j = 0; j < 4; ++j) { vals[i * 4 + j] = v[j]; s += v[j] * v[j]; }
    }
    const int ns = row_loc >> 4, col = row_loc & 15;
    #pragma unroll
    for (int quad = 0; quad < 4; ++quad) {
        u16x8 p;
        #pragma unroll
        for (int j = 0; j < 8; ++j) p[j] = f2bf(vals[quad * 8 + j]);
        *(u16x8*)(cb_swz + ((size_t)((c * 16 + ns * 8 + ks) * 64 + quad * 16 + col)) * 8) = p;
    }
    s += __shfl_xor(s, 1); s += __shfl_xor(s, 2); s += __shfl_xor(s, 4);
    if (ks == 0) norms[row] = s + 0.25f;
    if (c == 0 && t == 0) *loss_slot = 0.0f;
}

// ---------------- kernel 2: MFMA distance GEMM + packed argmin --------------
// 256 thr = 4 waves, 256 tokens/block (64/wave, m=4). Codes split in halves:
// grid 512 = 2 blocks/CU co-resident. Main loop is a counted-vmcnt phase
// schedule (T3/T4/T5): 3-deep LDS ring staged 2 chunks ahead via
// global_load_lds, raw s_barrier + s_waitcnt vmcnt(4) (never a full drain
// inside the loop), setprio(1) around each 32-MFMA cluster. Norms live in
// LDS so the loop's vmcnt stream contains ONLY ring loads (exact counting).
// X staging uses an XOR-swizzled layout (16B chunk ^= token>>2) making the
// bf16 transpose writes bank-conflict-free (was 8-way on 33M ds_write_u16).
__global__ __launch_bounds__(256, 2) void k_argmin(const float* __restrict__ x,
        const unsigned short* __restrict__ cb_swz, const float* __restrict__ norms,
        unsigned int* __restrict__ halfmin, float* __restrict__ loss_slot) {
    __shared__ __align__(16) unsigned short xs[32 * 264];     // 16896 B: X stage
    __shared__ __align__(16) unsigned short ring3[3][8192];   // 49152 B: B ring
    __shared__ __align__(16) float norms_s[2048];             //  8192 B
    __shared__ float wpart[4];
    const int t = threadIdx.x;
    const int lane = t & 63, w = t >> 6;
    const int col = lane & 15, quad = lane >> 4;
    const int bx = blockIdx.x;
    const int h = bx & 1;                  // code half
    const int tb = (bx >> 1) * 256;        // first token of block
    const int b = tb >> 11, s0 = tb & 2047;
    const float* xin = x + (size_t)b * DIM * SEQ;

    // prefetch B chunks 0,1 of this half into ring3[0],ring3[1] (overlaps
    // the whole X-staging prologue; drained once by its final syncthreads)
    {
        const char* src = (const char*)cb_swz + (size_t)h * 64 * 16384;
        #pragma unroll
        for (int cc = 0; cc < 2; ++cc)
            #pragma unroll
            for (int i = 0; i < 4; ++i)
                async_cp16(src + cc * 16384 + i * 4096 + w * 1024 + lane * 16,
                           (char*)ring3[cc] + i * 4096 + w * 1024);
    }
    // norms -> LDS once (removes global loads from the loop's vmcnt stream)
    {
        const float* ng = norms + h * 2048;
        *(floatx4*)&norms_s[t * 8]     = *(const floatx4*)(ng + t * 8);
        *(floatx4*)&norms_s[t * 8 + 4] = *(const floatx4*)(ng + t * 8 + 4);
    }

    // ---- X staging: 8 phases x 32 tokens; wave p>>1 grabs its A fragments.
    // Swizzle: 16B chunk index (d>>3) ^ token-quad q spreads the 16 writing
    // lanes (token stride 4) over all 32 banks -> 2 lanes/bank = free.
    bf16x8 af[4][8];
    float a2 = 0.0f;
    const int q = t & 7, dgp = t >> 3, sq = q * 4;
    for (int p = 0; p < 8; ++p) {
        const int sbase = s0 + p * 32 + sq;
        #pragma unroll
        for (int i = 0; i < 8; ++i) {
            const int d = i * 32 + dgp;
            floatx4 v = *(const floatx4*)(xin + (size_t)d * SEQ + sbase);
            a2 += v[0]*v[0] + v[1]*v[1] + v[2]*v[2] + v[3]*v[3];
            const int chs = (d >> 3) ^ q;            // swizzled 16B chunk
            #pragma unroll
            for (int j = 0; j < 4; ++j)
                xs[(sq + j) * 264 + chs * 8 + (d & 7)] = f2bf(-2.0f * v[j]);
        }
        __syncthreads();
        if ((p >> 1) == w) {
            const int mm = (p & 1) * 2;
            #pragma unroll
            for (int m2 = 0; m2 < 2; ++m2) {
                const int row = m2 * 16 + col;       // token = w*64+m*16+col
                const int swz = (row >> 2) & 7;
                #pragma unroll
                for (int ks = 0; ks < 8; ++ks)
                    af[mm + m2][ks] = *(const bf16x8*)
                        &xs[row * 264 + ((quad + ks * 4) ^ swz) * 8];
            }
        }
        __syncthreads();
    }
    // block-reduce a2; h==0 blocks contribute ||x||^2 part of the loss
    #pragma unroll
    for (int off = 1; off < 64; off <<= 1) a2 += __shfl_xor(a2, off);
    if (lane == 0) wpart[w] = a2;
    __syncthreads();   // final full drain: ring3[0],ring3[1] resident here
    if (t == 0 && h == 0)
        atomicAdd(loss_slot,
                  (wpart[0] + wpart[1] + wpart[2] + wpart[3]) * (1.25f / 16777216.0f));

    unsigned int minkey[4][4];
    #pragma unroll
    for (int m = 0; m < 4; ++m)
        #pragma unroll
        for (int r = 0; r < 4; ++r) minkey[m][r] = 0xFFFFFFFFu;

    const unsigned short* rcur = ring3[0];
    const unsigned short* rnxt = ring3[1];
    const unsigned short* rstg = ring3[2];
    const char* srcp = (const char*)cb_swz + ((size_t)h * 64 + 2) * 16384;
    const float* np = norms_s + col;
    unsigned int codev = (unsigned int)(h * 64 * 32 + col);

    #pragma unroll 1
    for (int c = 0; c < 64; ++c) {
        // ---- phase ns=0: bfrag+norm ds-loads, stage chunk c+2, barrier, MFMA
        float nv0 = np[0];
        bf16x8 bf0[8];
        #pragma unroll
        for (int ks = 0; ks < 8; ++ks)     // lane-contiguous 1KB: conflict-free
            bf0[ks] = *(const bf16x8*)&rcur[(ks * 64 + lane) * 8];
        if (c < 62) {
            #pragma unroll
            for (int i = 0; i < 4; ++i)
                async_cp16(srcp + i * 4096 + w * 1024 + lane * 16,
                           (const char*)rstg + i * 4096 + w * 1024);
        }
        __builtin_amdgcn_s_barrier();
        asm volatile("s_waitcnt lgkmcnt(0)" ::: "memory");
        __builtin_amdgcn_s_setprio(1);
        floatx4 acc0[4];
        #pragma unroll
        for (int m = 0; m < 4; ++m) acc0[m] = (floatx4){nv0, nv0, nv0, nv0};
        #pragma unroll
        for (int ks = 0; ks < 8; ++ks)     // 4 independent acc chains
            #pragma unroll
            for (int m = 0; m < 4; ++m)
                acc0[m] = __builtin_amdgcn_mfma_f32_16x16x32_bf16(
                              af[m][ks], bf0[ks], acc0[m], 0, 0, 0);
        __builtin_amdgcn_s_setprio(0);
        // ---- ns=1 ds-loads + ns=0 key update overlap the ns=0 MFMA tail
        float nv1 = np[16];
        bf16x8 bf1[8];
        #pragma unroll
        for (int ks = 0; ks < 8; ++ks)
            bf1[ks] = *(const bf16x8*)&rcur[((8 + ks) * 64 + lane) * 8];
        #pragma unroll
        for (int m = 0; m < 4; ++m)
            #pragma unroll
            for (int r = 0; r < 4; ++r) {
                unsigned int key = (__float_as_uint(acc0[m][r]) & 0xFFFFF000u) | codev;
                minkey[m][r] = key < minkey[m][r] ? key : minkey[m][r];
            }
        __builtin_amdgcn_s_barrier();
        asm volatile("s_waitcnt lgkmcnt(0)" ::: "memory");
        __builtin_amdgcn_s_setprio(1);
        floatx4 acc1[4];
        #pragma unroll
        for (int m = 0; m < 4; ++m) acc1[m] = (floatx4){nv1, nv1, nv1, nv1};
        #pragma unroll
        for (int ks = 0; ks < 8; ++ks)
            #pragma unroll
            for (int m = 0; m < 4; ++m)
                acc1[m] = __builtin_amdgcn_mfma_f32_16x16x32_bf16(
                              af[m][ks], bf1[ks], acc1[m], 0, 0, 0);
        __builtin_amdgcn_s_setprio(0);
        #pragma unroll
        for (int m = 0; m < 4; ++m)
            #pragma unroll
            for (int r = 0; r < 4; ++r) {
                unsigned int key = (__float_as_uint(acc1[m][r]) & 0xFFFFF000u)
                                   | (codev + 16);
                minkey[m][r] = key < minkey[m][r] ? key : minkey[m][r];
            }
        // publish: own chunk-(c+1) loads retired (in-order) => after the
        // barrier ALL waves' c+1 loads are resident; c+2's 4 stay in flight.
        if (c < 62) asm volatile("s_waitcnt vmcnt(4)" ::: "memory");
        else        asm volatile("s_waitcnt vmcnt(0)" ::: "memory");
        __builtin_amdgcn_s_barrier();
        const unsigned short* tmp = rcur; rcur = rnxt; rnxt = rstg; rstg = tmp;
        srcp += 16384; np += 32; codev += 32;
    }

    // ---- min over 16 column-lanes, write packed (dist|code) per token
    #pragma unroll
    for (int m = 0; m < 4; ++m)
        #pragma unroll
        for (int r = 0; r < 4; ++r) {
            unsigned int k = minkey[m][r];
            #pragma unroll
            for (int off = 8; off >= 1; off >>= 1) {
                unsigned int o = __shfl_xor(k, off);
                k = o < k ? o : k;
            }
            if (col == 0)
                halfmin[h * NTOK + tb + w * 64 + m * 16 + quad * 4 + r] = k;
        }
}

// ---------------- kernel 3: merge + gather (no x re-read) + loss ------------
// 256 thr, 64 tokens/block. Direct gather: thread (q=t&15) owns tokens q*4..+3,
// reads 4 cb scalars per d-step, stores coalesced 256B rows. Loss = sum of
// unpacked min distances (||x||^2 part added by k_argmin).
__global__ __launch_bounds__(256) void k_gather(const float* __restrict__ cb,
        const unsigned int* __restrict__ halfmin, float* __restrict__ out,
        float* __restrict__ loss_slot) {
    __shared__ int sidx[64];
    const int t = threadIdx.x;
    const int tb = blockIdx.x * 64;
    const int b = tb >> 11, s0 = tb & 2047;
    if (t < 64) {
        unsigned int k0 = halfmin[tb + t], k1 = halfmin[NTOK + tb + t];
        unsigned int km = k0 < k1 ? k0 : k1;
        sidx[t] = (int)(km & 0xFFFu);
        float dv = __uint_as_float(km & 0xFFFFF000u) - 0.25f;
        #pragma unroll
        for (int off = 32; off; off >>= 1) dv += __shfl_xor(dv, off);
        if (t == 0) atomicAdd(loss_slot, dv * (1.25f / 16777216.0f));
    }
    __syncthreads();
    const int q = t & 15, dg = t >> 4;
    int rows[4];
    #pragma unroll
    for (int k = 0; k < 4; ++k) rows[k] = sidx[q * 4 + k];
    #pragma unroll
    for (int i = 0; i < 16; ++i) {
        const int d = i * 16 + dg;
        floatx4 v;
        #pragma unroll
        for (int k = 0; k < 4; ++k) v[k] = cb[(size_t)rows[k] * DIM + d];
        *(floatx4*)(out + (size_t)b * DIM * SEQ + (size_t)d * SEQ + s0 + q * 4) = v;
    }
}

extern "C" void kernel_launch(void* const* d_in, const int* in_sizes, int n_in,
                              void* d_out, int out_size, void* d_ws, size_t ws_size,
                              hipStream_t stream) {
    const float* inputs   = (const float*)d_in[0];
    const float* codebook = (const float*)d_in[1];
    float* out = (float*)d_out;
    unsigned short* cb_swz = (unsigned short*)d_ws;                                  // 2 MB
    float* norms = (float*)((char*)d_ws + (size_t)K_CODES * DIM * 2);                // 16 KB
    unsigned int* halfmin = (unsigned int*)((char*)d_ws + (size_t)K_CODES * DIM * 2
                                            + K_CODES * 4);                          // 512 KB
    float* loss_slot = out + (out_size - 1);

    hipLaunchKernelGGL(k_prep,   dim3(K_CODES / 32),     dim3(256), 0, stream,
                       codebook, cb_swz, norms, loss_slot);
    hipLaunchKernelGGL(k_argmin, dim3(NTOK / 256 * 2),   dim3(256), 0, stream,
                       inputs, cb_swz, norms, halfmin, loss_slot);
    hipLaunchKernelGGL(k_gather, dim3(NTOK / 64),        dim3(256), 0, stream,
                       codebook, halfmin, out, loss_slot);
}